// Round 2
// baseline (324.227 us; speedup 1.0000x reference)
//
#include <hip/hip_runtime.h>
#include <stdint.h>

// ModulatedConv2d: B=8, C=512, O=512, K=3, WDIM=512, H=W=64
// Round-7: k_conv double-buffered 2-phase prefetch (catalog T3-minimal).
//   LDS 2x66KB=129KB (1 block/CU). Per flat iteration it=0..23:
//   STAGE(buf^1, it+1) issued async -> MFMA on buf -> single barrier.
//   Stage L2 delivery (~1150 cyc/CU) hides under MFMA phase (~1860 cyc/SIMD).
//   Weight factorization from round 6 retained (s on activation, D in epilogue).

#define MOD_SCALE  0.044194173824159216f   // 1/sqrt(512)
#define CONV_SCALE 0.014731391274719739f   // 1/sqrt(4608)

typedef __attribute__((ext_vector_type(4))) float f32x4;
typedef __attribute__((ext_vector_type(8))) short bf16x8;

__device__ inline unsigned short f2bf(float f) {   // round-to-nearest-even
  uint32_t u = __float_as_uint(f);
  uint32_t r = (u + 0x7fffu + ((u >> 16) & 1u)) >> 16;
  return (unsigned short)r;
}

__device__ inline void gload_lds16(const void* g, void* l) {
  __builtin_amdgcn_global_load_lds(
      (const __attribute__((address_space(1))) void*)g,
      (__attribute__((address_space(3))) void*)l, 16, 0, 0);
}

// ---------- style: s[b][c] = w[b].modw[c]*MOD_SCALE + modb[c] + 1 ----------
__global__ __launch_bounds__(256) void k_style(const float* __restrict__ w,
                                               const float* __restrict__ modw,
                                               const float* __restrict__ modb,
                                               float* __restrict__ s_out) {
  __shared__ float red[256];
  const int tid = threadIdx.x;
  const int sb = blockIdx.x;
  const int cb = sb & 7, b = sb >> 3;
  const int cl = tid >> 2, qq = tid & 3;
  const int c = (cb << 6) + cl;
  const float4* wd = (const float4*)(w + (b << 9) + (qq << 7));
  const float4* md = (const float4*)(modw + ((size_t)c << 9) + (qq << 7));
  float acc = 0.f;
#pragma unroll
  for (int i = 0; i < 32; ++i) {
    float4 a = wd[i], m = md[i];
    acc += a.x * m.x + a.y * m.y + a.z * m.z + a.w * m.w;
  }
  red[tid] = acc;
  __syncthreads();
  if (tid < 64) {
    float v = red[tid * 4] + red[tid * 4 + 1] + red[tid * 4 + 2] + red[tid * 4 + 3];
    int cc = (cb << 6) + tid;
    s_out[(b << 9) + cc] = v * MOD_SCALE + modb[cc] + 1.0f;
  }
}

// ---------- prep: xpad[b][py][px][c] = bf16(x[b][c][py-1][px-1] * s[b][c]) ----------
__global__ __launch_bounds__(256) void k_prep(const float* __restrict__ x,
                                              const float* __restrict__ s,
                                              unsigned short* __restrict__ xp) {
  __shared__ unsigned short smem[64 * 65];
  const int blk = blockIdx.x;
  const int tid = threadIdx.x;
  if (blk < 4096) {
    const int b = blk >> 9, r = blk & 511;
    const int c0 = ((r >> 6) << 6), p0 = ((r & 63) << 6);
    {
      const int pi = tid & 63, ci0 = tid >> 6;
      const float* src = x + (size_t)((b << 9) + c0 + ci0) * 4096 + p0 + pi;
      const float* sv = s + (b << 9) + c0 + ci0;   // wave-uniform scale
#pragma unroll
      for (int it = 0; it < 16; ++it)
        smem[(ci0 + (it << 2)) * 65 + pi] =
            f2bf(src[(size_t)(it << 2) * 4096] * sv[it << 2]);
    }
    __syncthreads();
    {
      const int cq = tid & 31, pq = tid >> 5;   // c-pair, pixel-in-group
#pragma unroll
      for (int it = 0; it < 8; ++it) {
        const int p = pq + (it << 3);
        const int gp = p0 + p;
        const int py = (gp >> 6) + 1, px = (gp & 63) + 1;
        uint32_t v = (uint32_t)smem[(cq << 1) * 65 + p] |
                     ((uint32_t)smem[((cq << 1) + 1) * 65 + p] << 16);
        ((uint32_t*)(xp + ((size_t)b * 4356 + py * 66 + px) * 512 + c0))[cq] = v;
      }
    }
  } else {
    // ---- zero pad border (260 segments x 8 batches) ----
    const int q = blk - 4096;
    const int b = q / 260, p = q - b * 260;
    int py, px;
    if (p < 66)       { py = 0;       px = p; }
    else if (p < 132) { py = 65;      px = p - 66; }
    else if (p < 196) { py = p - 131; px = 0; }
    else              { py = p - 195; px = 65; }
    uint32_t* dst = (uint32_t*)(xp + ((size_t)b * 4356 + py * 66 + px) * 512);
    dst[tid] = 0u;
  }
}

// ---------- fused demod + weight convert: one block per o ----------
__global__ __launch_bounds__(256) void k_fwd(const float* __restrict__ bw,
                                             const float* __restrict__ s,
                                             unsigned short* __restrict__ awT,
                                             float* __restrict__ d_out) {
  __shared__ float lw[4608];   // bw row, [c][tap]
  __shared__ float ls[4096];   // s, [b][c]
  __shared__ float red[32];
  const int tid = threadIdx.x;
  const int o = blockIdx.x;
  {
    const float4* src = (const float4*)(bw + (size_t)o * 4608);
    float4* dst = (float4*)lw;
#pragma unroll
    for (int i = 0; i < 4; ++i) dst[tid + (i << 8)] = src[tid + (i << 8)];
    if (tid < 128) dst[tid + 1024] = src[tid + 1024];
  }
  {
    const float4* src = (const float4*)s;
    float4* dst = (float4*)ls;
#pragma unroll
    for (int i = 0; i < 4; ++i) dst[tid + (i << 8)] = src[tid + (i << 8)];
  }
  __syncthreads();
  const int c0 = tid << 1;
  const int base = c0 * 9;
  float wq0 = 0.f, wq1 = 0.f;
#pragma unroll
  for (int j = 0; j < 9; ++j) {
    float a = lw[base + j];      wq0 += a * a;
    float b2 = lw[base + 9 + j]; wq1 += b2 * b2;
  }
  const int lane = tid & 63, wv = tid >> 6;
#pragma unroll
  for (int b = 0; b < 8; ++b) {
    float s0 = ls[(b << 9) + c0], s1 = ls[(b << 9) + c0 + 1];
    float v = wq0 * s0 * s0 + wq1 * s1 * s1;
#pragma unroll
    for (int off = 32; off > 0; off >>= 1) v += __shfl_down(v, off, 64);
    if (lane == 0) red[(b << 2) + wv] = v;
  }
  __syncthreads();
  if (tid < 8) {
    float a = red[tid << 2] + red[(tid << 2) + 1] + red[(tid << 2) + 2] + red[(tid << 2) + 3];
    d_out[(tid << 9) + o] = rsqrtf(a * (1.0f / 4608.0f)) * CONV_SCALE;
  }
  // bf16 convert of the raw base weight (once, no per-batch loop)
  uint32_t* dst = (uint32_t*)(awT + (size_t)o * 4608);
#pragma unroll
  for (int j = 0; j < 9; ++j)
    dst[(j << 8) + tid] = (uint32_t)f2bf(lw[base + j]) |
                          ((uint32_t)f2bf(lw[base + 9 + j]) << 16);
}

// ---------- main conv: 128x128 tile, BK=64, double-buffered 2-phase ----------
// LDS: 2 buffers x (As 3 tap-panels 128x64 + Bs 132-px halo strip x 64) = 129 KB.
// Flat it=0..23 (ky=it>>3, kb=it&7): STAGE(next) -> MFMA(cur) -> barrier.
__global__ __launch_bounds__(256, 1) void k_conv(const unsigned short* __restrict__ awT,
                                                 const unsigned short* __restrict__ xpad,
                                                 const float* __restrict__ dmod,
                                                 float* __restrict__ out) {
  __shared__ alignas(16) unsigned short As[2][3 * 8192];  // 2 x 48 KB
  __shared__ alignas(16) unsigned short Bs[2][8448];      // 2 x 16.5 KB
  const int tid = threadIdx.x;
  const int b  = blockIdx.z;
  const int m0 = blockIdx.y << 7;
  const int n0 = blockIdx.x << 7;
  const int y0 = n0 >> 6;

  const int srow = tid >> 3;                         // 0..31
  const int schk = ((tid & 7) - (srow & 7)) & 7;     // swizzled logical chunk
  const int scol = schk << 3;

  const unsigned short* A0 = awT + (size_t)(m0 + srow) * 4608 + scol;
  const size_t bx = (size_t)b * (66 * 66 * 512);

  const int lane = tid & 63;
  const int wv   = tid >> 6;
  const int moff = (wv >> 1) << 6;
  const int noff = (wv & 1) << 6;
  const int noffp = noff ? 66 : 0;   // halo-strip row base for this wave
  const int lm   = lane & 15;
  const int g4   = lane >> 4;

  // A reader offsets (ushort index into As[buf]); +kx*8192 selects panel
  int aoff[2];
#pragma unroll
  for (int h = 0; h < 2; ++h)
    aoff[h] = (moff + lm) * 64 + ((((h << 2) + g4) + moff + lm) & 7) * 8;
  // B reader offsets per (kx,h): row = noffp + lm + kx (+16j)
  int boff[3][2];
#pragma unroll
  for (int kx = 0; kx < 3; ++kx) {
    const int rb = noffp + lm + kx;
#pragma unroll
    for (int h = 0; h < 2; ++h)
      boff[kx][h] = rb * 64 + ((((h << 2) + g4) + rb) & 7) * 8;
  }

  f32x4 acc[4][4];
#pragma unroll
  for (int i = 0; i < 4; ++i)
#pragma unroll
    for (int j = 0; j < 4; ++j) acc[i][j] = (f32x4){0.f, 0.f, 0.f, 0.f};

  // stage one (ky,kb) K-slab into buffer `buf`
  auto stage = [&](int buf, int it) {
    const int ky = it >> 3, kcol = (it & 7) << 6;
    // A: 3 tap-panels
#pragma unroll
    for (int kx = 0; kx < 3; ++kx) {
      const unsigned short* Ap = A0 + ((ky * 3 + kx) << 9) + kcol;
#pragma unroll
      for (int g = 0; g < 4; ++g)
        gload_lds16(Ap + g * (32 * 4608),
                    &As[buf][(kx << 13) + (((g << 8) + tid) << 3)]);
    }
    // B: 132-pixel halo strip
    const unsigned short* Bp = xpad + bx + (size_t)((y0 + ky) * 66 + srow) * 512 + scol + kcol;
#pragma unroll
    for (int g = 0; g < 4; ++g)
      gload_lds16(Bp + g * (32 * 512), &Bs[buf][((g << 8) + tid) << 3]);
    if (tid < 32) gload_lds16(Bp + 128 * 512, &Bs[buf][8192 + tid * 8]);
  };

  stage(0, 0);
  __syncthreads();   // drains vmcnt(0): buf0 ready

  int cur = 0;
#pragma unroll 1
  for (int it = 0; it < 24; ++it) {
    if (it < 23) stage(cur ^ 1, it + 1);   // async prefetch into other buffer
    const unsigned short* Ab = As[cur];
    const unsigned short* Bb = Bs[cur];
#pragma unroll
    for (int kx = 0; kx < 3; ++kx) {
#pragma unroll
      for (int h = 0; h < 2; ++h) {
        bf16x8 af[4], bf[4];
        const unsigned short* pa = Ab + aoff[h] + (kx << 13);
        const unsigned short* pb = Bb + boff[kx][h];
#pragma unroll
        for (int i = 0; i < 4; ++i) af[i] = *(const bf16x8*)(pa + (i << 10));
#pragma unroll
        for (int j = 0; j < 4; ++j) bf[j] = *(const bf16x8*)(pb + (j << 10));
#pragma unroll
        for (int i = 0; i < 4; ++i)
#pragma unroll
          for (int j = 0; j < 4; ++j)
            acc[i][j] = __builtin_amdgcn_mfma_f32_16x16x32_bf16(af[i], bf[j], acc[i][j], 0, 0, 0);
      }
    }
    __syncthreads();   // drains prefetch vmcnt + releases cur for overwrite
    cur ^= 1;
  }

  // epilogue: D layout col=lane&15 (pixel), row=(lane>>4)*4+reg (o); apply D[b][o]
  const float* dB = dmod + (b << 9) + m0 + moff;
  float* op = out + (size_t)((b << 9) + m0 + moff) * 4096 + n0 + noff;
#pragma unroll
  for (int i = 0; i < 4; ++i) {
#pragma unroll
    for (int r = 0; r < 4; ++r) {
      const int m = i * 16 + (g4 << 2) + r;
      const float dm = dB[m];
#pragma unroll
      for (int j = 0; j < 4; ++j)
        op[(size_t)m * 4096 + (j << 4) + lm] = acc[i][j][r] * dm;
    }
  }
}

extern "C" void kernel_launch(void* const* d_in, const int* in_sizes, int n_in,
                              void* d_out, int out_size, void* d_ws, size_t ws_size,
                              hipStream_t stream) {
  const float* x    = (const float*)d_in[0];   // (8,512,64,64)
  const float* w    = (const float*)d_in[1];   // (8,512)
  const float* bw   = (const float*)d_in[2];   // (1,512,512,3,3)
  const float* modw = (const float*)d_in[3];   // (512,512)
  const float* modb = (const float*)d_in[4];   // (512,)
  float* out = (float*)d_out;                  // (8,512,64,64) fp32
  char* ws = (char*)d_ws;

  float* s_buf = (float*)(ws);                              // 16 KB
  float* d_buf = (float*)(ws + 16384);                      // 16 KB
  unsigned short* awT  = (unsigned short*)(ws + 32768);     // 4,718,592 B
  unsigned short* xpad = (unsigned short*)(ws + 4751360);   // 35,684,352 B

  (void)in_sizes; (void)n_in; (void)out_size; (void)ws_size;

  k_style<<<64,   256, 0, stream>>>(w, modw, modb, s_buf);
  k_prep <<<6176, 256, 0, stream>>>(x, s_buf, xpad);
  k_fwd  <<<512,  256, 0, stream>>>(bw, s_buf, awT, d_buf);
  k_conv <<<dim3(32, 4, 8), 256, 0, stream>>>(awT, xpad, d_buf, out);
}

// Round 3
// 258.654 us; speedup vs baseline: 1.2535x; 1.2535x over previous
//
#include <hip/hip_runtime.h>
#include <stdint.h>

// ModulatedConv2d: B=8, C=512, O=512, K=3, WDIM=512, H=W=64
// Round-8: k_conv reverted to round-1 single-buffer (2 blocks/CU inter-block
//   overlap beats explicit dbuf at 1 block/CU — round-2 post-mortem).
//   k_prep rewritten for bandwidth: per-(b,y) row transpose, float4 reads
//   (1KB/wave-instr), LDS [px][cpair] u32 pad-260, uint4 stores (contiguous
//   1KB per pixel). Was scalar 4B loads + scattered 128B stores (~1 TB/s).

#define MOD_SCALE  0.044194173824159216f   // 1/sqrt(512)
#define CONV_SCALE 0.014731391274719739f   // 1/sqrt(4608)

typedef __attribute__((ext_vector_type(4))) float f32x4;
typedef __attribute__((ext_vector_type(8))) short bf16x8;

__device__ inline unsigned short f2bf(float f) {   // round-to-nearest-even
  uint32_t u = __float_as_uint(f);
  uint32_t r = (u + 0x7fffu + ((u >> 16) & 1u)) >> 16;
  return (unsigned short)r;
}

__device__ inline void gload_lds16(const void* g, void* l) {
  __builtin_amdgcn_global_load_lds(
      (const __attribute__((address_space(1))) void*)g,
      (__attribute__((address_space(3))) void*)l, 16, 0, 0);
}

// ---------- style: s[b][c] = w[b].modw[c]*MOD_SCALE + modb[c] + 1 ----------
__global__ __launch_bounds__(256) void k_style(const float* __restrict__ w,
                                               const float* __restrict__ modw,
                                               const float* __restrict__ modb,
                                               float* __restrict__ s_out) {
  __shared__ float red[256];
  const int tid = threadIdx.x;
  const int sb = blockIdx.x;
  const int cb = sb & 7, b = sb >> 3;
  const int cl = tid >> 2, qq = tid & 3;
  const int c = (cb << 6) + cl;
  const float4* wd = (const float4*)(w + (b << 9) + (qq << 7));
  const float4* md = (const float4*)(modw + ((size_t)c << 9) + (qq << 7));
  float acc = 0.f;
#pragma unroll
  for (int i = 0; i < 32; ++i) {
    float4 a = wd[i], m = md[i];
    acc += a.x * m.x + a.y * m.y + a.z * m.z + a.w * m.w;
  }
  red[tid] = acc;
  __syncthreads();
  if (tid < 64) {
    float v = red[tid * 4] + red[tid * 4 + 1] + red[tid * 4 + 2] + red[tid * 4 + 3];
    int cc = (cb << 6) + tid;
    s_out[(b << 9) + cc] = v * MOD_SCALE + modb[cc] + 1.0f;
  }
}

// ---------- prep: xpad[b][py][px][c] = bf16(x[b][c][py-1][px-1] * s[b][c]) ----------
// blk < 512: one block per (b, y) image row. Phase 1: float4 reads of 512 c-rows
// x 64 px, pack c-pairs -> LDS [px][cpair] (pad 260 u32, 16B aligned). Phase 2:
// each wave stores one pixel's contiguous 1KB channel vector per iteration.
// blk >= 512: zero the 1-px border (260 segments x 8 batches).
__global__ __launch_bounds__(256) void k_prep(const float* __restrict__ x,
                                              const float* __restrict__ s,
                                              unsigned short* __restrict__ xp) {
  __shared__ uint32_t tb[64 * 260];   // 66,560 B -> 2 blocks/CU
  const int blk = blockIdx.x;
  const int tid = threadIdx.x;
  if (blk < 512) {
    const int b = blk >> 6, y = blk & 63;
    const int px4 = tid & 15;          // which float4 of the 64-px row
    const int cp  = tid >> 4;          // 0..15
    const float* xb = x + (size_t)(b << 9) * 4096 + (y << 6) + (px4 << 2);
    const float* sb = s + (b << 9);
#pragma unroll
    for (int it = 0; it < 16; ++it) {
      const int cpair = cp + (it << 4);        // 0..255
      const int c0 = cpair << 1;
      const float4 a0 = *(const float4*)(xb + (size_t)c0 * 4096);
      const float4 a1 = *(const float4*)(xb + (size_t)(c0 + 1) * 4096);
      const float s0 = sb[c0], s1 = sb[c0 + 1];
      const int pxb = px4 << 2;
      tb[(pxb + 0) * 260 + cpair] = (uint32_t)f2bf(a0.x * s0) | ((uint32_t)f2bf(a1.x * s1) << 16);
      tb[(pxb + 1) * 260 + cpair] = (uint32_t)f2bf(a0.y * s0) | ((uint32_t)f2bf(a1.y * s1) << 16);
      tb[(pxb + 2) * 260 + cpair] = (uint32_t)f2bf(a0.z * s0) | ((uint32_t)f2bf(a1.z * s1) << 16);
      tb[(pxb + 3) * 260 + cpair] = (uint32_t)f2bf(a0.w * s0) | ((uint32_t)f2bf(a1.w * s1) << 16);
    }
    __syncthreads();
    const int wv = tid >> 6, l = tid & 63;
    uint32_t* xpw = (uint32_t*)xp;
#pragma unroll
    for (int it = 0; it < 16; ++it) {
      const int px = (wv << 4) + it;
      const uint4 v = *(const uint4*)(tb + px * 260 + (l << 2));  // 16B-aligned
      const size_t base = ((size_t)b * 4356 + (size_t)(y + 1) * 66 + (px + 1)) << 8;
      ((uint4*)(xpw + base))[l] = v;   // wave writes contiguous 1 KB
    }
  } else {
    // ---- zero pad border (260 segments x 8 batches) ----
    const int q = blk - 512;
    const int b = q / 260, p = q - b * 260;
    int py, px;
    if (p < 66)       { py = 0;       px = p; }
    else if (p < 132) { py = 65;      px = p - 66; }
    else if (p < 196) { py = p - 131; px = 0; }
    else              { py = p - 195; px = 65; }
    uint32_t* dst = (uint32_t*)(xp + ((size_t)b * 4356 + py * 66 + px) * 512);
    dst[tid] = 0u;
  }
}

// ---------- fused demod + weight convert: one block per o ----------
__global__ __launch_bounds__(256) void k_fwd(const float* __restrict__ bw,
                                             const float* __restrict__ s,
                                             unsigned short* __restrict__ awT,
                                             float* __restrict__ d_out) {
  __shared__ float lw[4608];   // bw row, [c][tap]
  __shared__ float ls[4096];   // s, [b][c]
  __shared__ float red[32];
  const int tid = threadIdx.x;
  const int o = blockIdx.x;
  {
    const float4* src = (const float4*)(bw + (size_t)o * 4608);
    float4* dst = (float4*)lw;
#pragma unroll
    for (int i = 0; i < 4; ++i) dst[tid + (i << 8)] = src[tid + (i << 8)];
    if (tid < 128) dst[tid + 1024] = src[tid + 1024];
  }
  {
    const float4* src = (const float4*)s;
    float4* dst = (float4*)ls;
#pragma unroll
    for (int i = 0; i < 4; ++i) dst[tid + (i << 8)] = src[tid + (i << 8)];
  }
  __syncthreads();
  const int c0 = tid << 1;
  const int base = c0 * 9;
  float wq0 = 0.f, wq1 = 0.f;
#pragma unroll
  for (int j = 0; j < 9; ++j) {
    float a = lw[base + j];      wq0 += a * a;
    float b2 = lw[base + 9 + j]; wq1 += b2 * b2;
  }
  const int lane = tid & 63, wv = tid >> 6;
#pragma unroll
  for (int b = 0; b < 8; ++b) {
    float s0 = ls[(b << 9) + c0], s1 = ls[(b << 9) + c0 + 1];
    float v = wq0 * s0 * s0 + wq1 * s1 * s1;
#pragma unroll
    for (int off = 32; off > 0; off >>= 1) v += __shfl_down(v, off, 64);
    if (lane == 0) red[(b << 2) + wv] = v;
  }
  __syncthreads();
  if (tid < 8) {
    float a = red[tid << 2] + red[(tid << 2) + 1] + red[(tid << 2) + 2] + red[(tid << 2) + 3];
    d_out[(tid << 9) + o] = rsqrtf(a * (1.0f / 4608.0f)) * CONV_SCALE;
  }
  // bf16 convert of the raw base weight (once, no per-batch loop)
  uint32_t* dst = (uint32_t*)(awT + (size_t)o * 4608);
#pragma unroll
  for (int j = 0; j < 9; ++j)
    dst[(j << 8) + tid] = (uint32_t)f2bf(lw[base + j]) |
                          ((uint32_t)f2bf(lw[base + 9 + j]) << 16);
}

// ---------- main conv: 128x128 tile, BK=64, B-halo shared across kx taps ----------
// Round-1 verified structure: single buffer, 66 KB LDS, 2 blocks/CU.
__global__ __launch_bounds__(256, 2) void k_conv(const unsigned short* __restrict__ awT,
                                                 const unsigned short* __restrict__ xpad,
                                                 const float* __restrict__ dmod,
                                                 float* __restrict__ out) {
  __shared__ alignas(16) unsigned short As[3 * 8192];  // 48 KB
  __shared__ alignas(16) unsigned short Bs[8448];      // 16.5 KB
  const int tid = threadIdx.x;
  const int b  = blockIdx.z;
  const int m0 = blockIdx.y << 7;
  const int n0 = blockIdx.x << 7;
  const int y0 = n0 >> 6;

  const int srow = tid >> 3;                         // 0..31
  const int schk = ((tid & 7) - (srow & 7)) & 7;     // swizzled logical chunk
  const int scol = schk << 3;

  const unsigned short* A0 = awT + (size_t)(m0 + srow) * 4608 + scol;
  const size_t bx = (size_t)b * (66 * 66 * 512);

  const int lane = tid & 63;
  const int wv   = tid >> 6;
  const int moff = (wv >> 1) << 6;
  const int noff = (wv & 1) << 6;
  const int noffp = noff ? 66 : 0;   // halo-strip row base for this wave
  const int lm   = lane & 15;
  const int g4   = lane >> 4;

  // A reader bases (chunk const across i since 16i = 0 mod 8); +kx*8192 selects panel
  const unsigned short* ardA[2];
#pragma unroll
  for (int h = 0; h < 2; ++h)
    ardA[h] = As + (moff + lm) * 64 + ((((h << 2) + g4) + moff + lm) & 7) * 8;
  // B reader bases per (kx,h): row = noffp + lm + kx (+16j)
  const unsigned short* ardB[3][2];
#pragma unroll
  for (int kx = 0; kx < 3; ++kx) {
    const int rb = noffp + lm + kx;
#pragma unroll
    for (int h = 0; h < 2; ++h)
      ardB[kx][h] = Bs + rb * 64 + ((((h << 2) + g4) + rb) & 7) * 8;
  }

  f32x4 acc[4][4];
#pragma unroll
  for (int i = 0; i < 4; ++i)
#pragma unroll
    for (int j = 0; j < 4; ++j) acc[i][j] = (f32x4){0.f, 0.f, 0.f, 0.f};

#pragma unroll 1
  for (int ky = 0; ky < 3; ++ky) {
    const unsigned short* Bp0 = xpad + bx + (size_t)((y0 + ky) * 66 + srow) * 512 + scol;
#pragma unroll 1
    for (int kb = 0; kb < 8; ++kb) {
      const int kcol = kb << 6;
      // stage 3 A tap-panels
#pragma unroll
      for (int kx = 0; kx < 3; ++kx) {
        const unsigned short* Ap = A0 + ((ky * 3 + kx) << 9) + kcol;
#pragma unroll
        for (int g = 0; g < 4; ++g)
          gload_lds16(Ap + g * (32 * 4608), As + ((kx << 13) + (((g << 8) + tid) << 3)));
      }
      // stage B halo strip: 132 rows (linear: pixel offset = (y0+ky)*66 + hr)
      const unsigned short* Bp = Bp0 + kcol;
#pragma unroll
      for (int g = 0; g < 4; ++g)
        gload_lds16(Bp + g * (32 * 512), Bs + (((g << 8) + tid) << 3));
      if (tid < 32) gload_lds16(Bp + 128 * 512, Bs + 8192 + tid * 8);
      __syncthreads();
#pragma unroll
      for (int kx = 0; kx < 3; ++kx) {
#pragma unroll
        for (int h = 0; h < 2; ++h) {
          bf16x8 af[4], bf[4];
          const unsigned short* pa = ardA[h] + (kx << 13);
          const unsigned short* pb = ardB[kx][h];
#pragma unroll
          for (int i = 0; i < 4; ++i) af[i] = *(const bf16x8*)(pa + (i << 10));
#pragma unroll
          for (int j = 0; j < 4; ++j) bf[j] = *(const bf16x8*)(pb + (j << 10));
#pragma unroll
          for (int i = 0; i < 4; ++i)
#pragma unroll
            for (int j = 0; j < 4; ++j)
              acc[i][j] = __builtin_amdgcn_mfma_f32_16x16x32_bf16(af[i], bf[j], acc[i][j], 0, 0, 0);
        }
      }
      __syncthreads();
    }
  }

  // epilogue: D layout col=lane&15 (pixel), row=(lane>>4)*4+reg (o); apply D[b][o]
  const float* dB = dmod + (b << 9) + m0 + moff;
  float* op = out + (size_t)((b << 9) + m0 + moff) * 4096 + n0 + noff;
#pragma unroll
  for (int i = 0; i < 4; ++i) {
#pragma unroll
    for (int r = 0; r < 4; ++r) {
      const int m = i * 16 + (g4 << 2) + r;
      const float dm = dB[m];
#pragma unroll
      for (int j = 0; j < 4; ++j)
        op[(size_t)m * 4096 + (j << 4) + lm] = acc[i][j][r] * dm;
    }
  }
}

extern "C" void kernel_launch(void* const* d_in, const int* in_sizes, int n_in,
                              void* d_out, int out_size, void* d_ws, size_t ws_size,
                              hipStream_t stream) {
  const float* x    = (const float*)d_in[0];   // (8,512,64,64)
  const float* w    = (const float*)d_in[1];   // (8,512)
  const float* bw   = (const float*)d_in[2];   // (1,512,512,3,3)
  const float* modw = (const float*)d_in[3];   // (512,512)
  const float* modb = (const float*)d_in[4];   // (512,)
  float* out = (float*)d_out;                  // (8,512,64,64) fp32
  char* ws = (char*)d_ws;

  float* s_buf = (float*)(ws);                              // 16 KB
  float* d_buf = (float*)(ws + 16384);                      // 16 KB
  unsigned short* awT  = (unsigned short*)(ws + 32768);     // 4,718,592 B
  unsigned short* xpad = (unsigned short*)(ws + 4751360);   // 35,684,352 B

  (void)in_sizes; (void)n_in; (void)out_size; (void)ws_size;

  k_style<<<64,   256, 0, stream>>>(w, modw, modb, s_buf);
  k_fwd  <<<512,  256, 0, stream>>>(bw, s_buf, awT, d_buf);
  k_prep <<<2592, 256, 0, stream>>>(x, s_buf, xpad);
  k_conv <<<dim3(32, 4, 8), 256, 0, stream>>>(awT, xpad, d_buf, out);
}